// Round 2
// baseline (746.908 us; speedup 1.0000x reference)
//
#include <hip/hip_runtime.h>
#include <hip/hip_bf16.h>
#include <cstdint>

typedef __attribute__((ext_vector_type(8))) short short8;
typedef __attribute__((ext_vector_type(4))) float floatx4;
typedef __attribute__((ext_vector_type(16))) float floatx16;

#define Bdim 32
#define Tdim 48
#define Ldim 400
#define Hdim 512
#define Edim 128
#define Vdim 50000
#define VEdim 50100
#define BTdim 1536
#define CATdim 1536
#define NPAD 50048     // 782*64; also 391*128
#define MTILES 96      // BTdim/16
#define NPART 782      // 64-col tiles in pass 1

__device__ __forceinline__ short f2bf(float x){
    __hip_bfloat16 h = __float2bfloat16(x);
    union { __hip_bfloat16 h; short s; } u; u.h = h; return u.s;
}

__device__ __forceinline__ float wred(float s){
    #pragma unroll
    for (int off = 32; off; off >>= 1) s += __shfl_xor(s, off, 64);
    return s;
}

// ---------------- fp32 tiled GEMM body, C = A(MxK) @ B(KxN), row-major ----
// register double-buffer prefetch; optional bf16 output (template).
template<bool BF16>
__device__ __forceinline__ void gemm_nn_body(
    const float* __restrict__ A, int lda,
    const float* __restrict__ B, int ldb,
    float* __restrict__ C, short* __restrict__ Cb, int ldc,
    int M, int N, int K, int m0, int n0,
    float (*As)[68], float (*Bs)[68])
{
    const int tid = threadIdx.x;
    const int tx = tid & 15, ty = tid >> 4;
    const int ar = tid >> 2, ac = (tid & 3) * 4;   // A: row in tile, col*4
    const int br = tid >> 4, bc = (tid & 15) * 4;  // B: row in tile, col*4
    float acc[4][4] = {};
    float4 va = make_float4(0.f,0.f,0.f,0.f);
    float4 vb = make_float4(0.f,0.f,0.f,0.f);
    if (m0 + ar < M) va = *(const float4*)(A + (size_t)(m0+ar)*lda + ac);
    if (n0 + bc < N) vb = *(const float4*)(B + (size_t)br*ldb + n0 + bc);
    for (int k0 = 0; k0 < K; k0 += 16){
        As[ac+0][ar]=va.x; As[ac+1][ar]=va.y; As[ac+2][ar]=va.z; As[ac+3][ar]=va.w;
        Bs[br][bc+0]=vb.x; Bs[br][bc+1]=vb.y; Bs[br][bc+2]=vb.z; Bs[br][bc+3]=vb.w;
        __syncthreads();
        const int kn = k0 + 16;
        if (kn < K){
            va = make_float4(0.f,0.f,0.f,0.f);
            vb = make_float4(0.f,0.f,0.f,0.f);
            if (m0 + ar < M) va = *(const float4*)(A + (size_t)(m0+ar)*lda + kn + ac);
            if (n0 + bc < N) vb = *(const float4*)(B + (size_t)(kn+br)*ldb + n0 + bc);
        }
        #pragma unroll
        for (int k=0;k<16;k++){
            float a[4], b[4];
            #pragma unroll
            for (int i=0;i<4;i++) a[i] = As[k][ty*4+i];
            #pragma unroll
            for (int j=0;j<4;j++) b[j] = Bs[k][tx*4+j];
            #pragma unroll
            for (int i=0;i<4;i++)
                #pragma unroll
                for (int j=0;j<4;j++)
                    acc[i][j] += a[i]*b[j];
        }
        __syncthreads();
    }
    #pragma unroll
    for (int i=0;i<4;i++){
        int m = m0 + ty*4 + i;
        if (m >= M) continue;
        #pragma unroll
        for (int j=0;j<4;j++){
            int n = n0 + tx*4 + j;
            if (n < N){
                if (BF16) Cb[(size_t)m*ldc + n] = f2bf(acc[i][j]);
                else      C[(size_t)m*ldc + n]  = acc[i][j];
            }
        }
    }
}

// ---------------- fp32 tiled GEMM body, C = A(MxK) @ B(NxK)^T -------------
__device__ __forceinline__ void gemm_nt_body(
    const float* __restrict__ A, int lda,
    const float* __restrict__ B, int ldb,
    float* __restrict__ C, int ldc,
    int M, int N, int K, int m0, int n0,
    float (*As)[68], float (*Bs)[68])
{
    const int tid = threadIdx.x;
    const int tx = tid & 15, ty = tid >> 4;
    const int r = tid >> 2, c = (tid & 3) * 4;
    float acc[4][4] = {};
    float4 va = make_float4(0.f,0.f,0.f,0.f);
    float4 vb = make_float4(0.f,0.f,0.f,0.f);
    if (m0 + r < M) va = *(const float4*)(A + (size_t)(m0+r)*lda + c);
    if (n0 + r < N) vb = *(const float4*)(B + (size_t)(n0+r)*ldb + c);
    for (int k0 = 0; k0 < K; k0 += 16){
        As[c+0][r]=va.x; As[c+1][r]=va.y; As[c+2][r]=va.z; As[c+3][r]=va.w;
        Bs[c+0][r]=vb.x; Bs[c+1][r]=vb.y; Bs[c+2][r]=vb.z; Bs[c+3][r]=vb.w;
        __syncthreads();
        const int kn = k0 + 16;
        if (kn < K){
            va = make_float4(0.f,0.f,0.f,0.f);
            vb = make_float4(0.f,0.f,0.f,0.f);
            if (m0 + r < M) va = *(const float4*)(A + (size_t)(m0+r)*lda + kn + c);
            if (n0 + r < N) vb = *(const float4*)(B + (size_t)(n0+r)*ldb + kn + c);
        }
        #pragma unroll
        for (int k=0;k<16;k++){
            float a[4], b[4];
            #pragma unroll
            for (int i=0;i<4;i++) a[i] = As[k][ty*4+i];
            #pragma unroll
            for (int j=0;j<4;j++) b[j] = Bs[k][tx*4+j];
            #pragma unroll
            for (int i=0;i<4;i++)
                #pragma unroll
                for (int j=0;j<4;j++)
                    acc[i][j] += a[i]*b[j];
        }
        __syncthreads();
    }
    #pragma unroll
    for (int i=0;i<4;i++){
        int m = m0 + ty*4 + i;
        if (m >= M) continue;
        #pragma unroll
        for (int j=0;j<4;j++){
            int n = n0 + tx*4 + j;
            if (n < N) C[(size_t)m*ldc + n] = acc[i][j];
        }
    }
}

// ============ launch A: p12 GEMMs + h-copy + Wv transpose + q_enc/q_dec +
//              zero(sums). All jobs depend only on kernel inputs. ==========
__global__ __launch_bounds__(256) void kA(
    const float* __restrict__ dec, const float* __restrict__ Wenc,
    const float* __restrict__ Wdec, float* __restrict__ P1, float* __restrict__ P2,
    float* __restrict__ cat,
    const float* __restrict__ Wv, short* __restrict__ Wt,
    const float* __restrict__ enc, const float* __restrict__ wptr,
    float* __restrict__ q_enc, float* __restrict__ q_dec,
    float* __restrict__ sums)
{
    __shared__ float As[16][68];
    __shared__ float Bs[16][68];
    int bid = blockIdx.x;
    if (bid < 384){
        int z = bid / 192, r = bid % 192;
        gemm_nn_body<false>(dec, Hdim, z ? Wdec : Wenc, Hdim,
                            z ? P2 : P1, nullptr, Hdim,
                            BTdim, Hdim, Hdim, (r>>3)*64, (r&7)*64, As, Bs);
        return;
    }
    bid -= 384;
    if (bid < 768){
        // copy h into cat[:, 0:512], float4
        int idx = bid*256 + threadIdx.x;          // 0..196607
        int m = idx >> 7, j = (idx & 127) << 2;
        *(float4*)(cat + (size_t)m*CATdim + j) =
            *(const float4*)(dec + (size_t)m*Hdim + j);
        return;
    }
    bid -= 768;
    if (bid < 6256){
        // W_vocab (128 x 50000) -> bf16 transposed (50048 x 128)
        float (*tile)[33] = reinterpret_cast<float(*)[33]>(&As[0][0]);  // 1056<=1088
        int n0 = (bid % 1564)*32, k0 = (bid / 1564)*32;
        int x = threadIdx.x & 31, y0 = threadIdx.x >> 5;  // 32 x 8
        for (int yy=y0; yy<32; yy+=8){
            int n = n0 + x;
            tile[yy][x] = (n < Vdim) ? Wv[(size_t)(k0+yy)*Vdim + n] : 0.f;
        }
        __syncthreads();
        for (int yy=y0; yy<32; yy+=8){
            int n = n0 + yy;
            if (n < NPAD) Wt[(size_t)n*Edim + k0 + x] = f2bf(tile[x][yy]);
        }
        return;
    }
    bid -= 6256;
    if (bid < 128){
        // q_enc[b][l] = enc[b][l] . w2 ; q_dec[b][t] = dec[b][t] . w3
        int b = bid >> 2, part = bid & 3;
        int wv = threadIdx.x >> 6, lane = threadIdx.x & 63;
        const float* w2 = wptr + Hdim;
        const float* w3 = wptr + 2*Hdim;
        for (int r = part*100 + wv; r < part*100 + 100; r += 4){
            const float* rp = enc + ((size_t)b*Ldim + r)*Hdim;
            float s = 0.f;
            #pragma unroll
            for (int i = 0; i < 8; i++) s += rp[lane + i*64]*w2[lane + i*64];
            s = wred(s);
            if (lane == 0) q_enc[b*Ldim + r] = s;
        }
        if (part == 0){
            for (int r = wv; r < Tdim; r += 4){
                const float* rp = dec + ((size_t)b*Tdim + r)*Hdim;
                float s = 0.f;
                #pragma unroll
                for (int i = 0; i < 8; i++) s += rp[lane + i*64]*w3[lane + i*64];
                s = wred(s);
                if (lane == 0) q_dec[b*Tdim + r] = s;
            }
        }
        return;
    }
    // zero the exp-sum accumulator
    for (int i = threadIdx.x; i < BTdim; i += 256) sums[i] = 0.f;
}

// ============ launch B: e-scores + s-scores (NT GEMMs) ====================
__global__ __launch_bounds__(256) void kB(
    const float* __restrict__ P1, const float* __restrict__ P2,
    const float* __restrict__ enc, const float* __restrict__ dec,
    float* __restrict__ ebuf, float* __restrict__ sbuf)
{
    __shared__ float As[16][68];
    __shared__ float Bs[16][68];
    int bid = blockIdx.x;
    if (bid < 224){
        int z = bid / 7, x = bid % 7;
        gemm_nt_body(P1 + (size_t)z*Tdim*Hdim, Hdim,
                     enc + (size_t)z*Ldim*Hdim, Hdim,
                     ebuf + (size_t)z*Tdim*Ldim, Ldim,
                     Tdim, Ldim, Hdim, 0, x*64, As, Bs);
    } else {
        int z = bid - 224;
        gemm_nt_body(P2 + (size_t)z*Tdim*Hdim, Hdim,
                     dec + (size_t)z*Tdim*Hdim, Hdim,
                     sbuf + (size_t)z*Tdim*Tdim, Tdim,
                     Tdim, Tdim, Hdim, 0, 0, As, Bs);
    }
}

// ============ launch C: per-b temporal scan + l-normalize + masked decoder
//              softmax + pointer gate. 32 blocks x 512 threads. =============
__global__ __launch_bounds__(512) void kC(
    const float* __restrict__ e, float* __restrict__ att, float* __restrict__ sbuf,
    const float* __restrict__ dec, const float* __restrict__ wptr,
    const float* __restrict__ bptr,
    const float* __restrict__ q_enc, const float* __restrict__ q_dec,
    float* __restrict__ pg)
{
    __shared__ float att_s[Tdim][Ldim];   // 75 KB
    __shared__ float dE[Tdim], dD[Tdim], dH[Tdim];
    const int b = blockIdx.x;
    const int tid = threadIdx.x;
    // temporal prefix scan over t (one thread per l)
    if (tid < Ldim){
        const float* ep = e + (size_t)b*Tdim*Ldim + tid;
        float acc = 0.f;
        for (int t = 0; t < Tdim; ++t){
            float x = __expf(ep[t*Ldim]);
            att_s[t][tid] = x / (t ? acc : 1.f);
            acc += x;
        }
    }
    __syncthreads();
    const int wv = tid >> 6, lane = tid & 63;
    // per-row normalize + dot with q_enc; write normalized att to global
    for (int t = wv; t < Tdim; t += 8){
        float s1 = 0.f, s2 = 0.f;
        for (int l = lane; l < Ldim; l += 64){
            float a = att_s[t][l];
            s1 += a;
            s2 += a * q_enc[b*Ldim + l];
        }
        s1 = wred(s1); s2 = wred(s2);
        float inv = 1.f/s1;
        if (lane == 0) dE[t] = s2*inv;
        for (int l = lane; l < Ldim; l += 64)
            att[(size_t)(b*Tdim + t)*Ldim + l] = att_s[t][l]*inv;
    }
    // h . w1 per row
    for (int t = wv; t < Tdim; t += 8){
        const float* hp = dec + ((size_t)b*Tdim + t)*Hdim;
        float s = 0.f;
        #pragma unroll
        for (int i = 0; i < 8; i++) s += hp[lane + i*64]*wptr[lane + i*64];
        s = wred(s);
        if (lane == 0) dH[t] = s;
    }
    // masked decoder softmax per row + dot with q_dec
    for (int t = wv; t < Tdim; t += 8){
        float* row = sbuf + ((size_t)b*Tdim + t)*Tdim;
        if (t == 0){
            if (lane < Tdim) row[lane] = 0.f;
            if (lane == 0) dD[0] = 0.f;
        } else {
            float v = (lane < t) ? row[lane] : -1e30f;
            float mx = v;
            #pragma unroll
            for (int off = 32; off; off >>= 1) mx = fmaxf(mx, __shfl_xor(mx, off, 64));
            float ex = (lane < t) ? __expf(v - mx) : 0.f;
            float sm = wred(ex);
            float nv = ex / sm;
            if (lane < Tdim) row[lane] = nv;
            float d = (lane < Tdim) ? nv * q_dec[b*Tdim + lane] : 0.f;
            d = wred(d);
            if (lane == 0) dD[t] = d;
        }
    }
    __syncthreads();
    if (tid < Tdim){
        float tot = dH[tid] + dE[tid] + dD[tid] + bptr[0];
        pg[b*Tdim + tid] = 1.f/(1.f + __expf(-tot));
    }
}

// ============ launch D: enc_ctx + dec_ctx GEMMs into cat ==================
__global__ __launch_bounds__(256) void kD(
    const float* __restrict__ att, const float* __restrict__ sbuf,
    const float* __restrict__ enc, const float* __restrict__ dec,
    float* __restrict__ cat)
{
    __shared__ float As[16][68];
    __shared__ float Bs[16][68];
    int bid = blockIdx.x;
    if (bid < 256){
        int z = bid >> 3, x = bid & 7;
        gemm_nn_body<false>(att + (size_t)z*Tdim*Ldim, Ldim,
                            enc + (size_t)z*Ldim*Hdim, Hdim,
                            cat + (size_t)z*Tdim*CATdim + Hdim, nullptr, CATdim,
                            Tdim, Hdim, Ldim, 0, x*64, As, Bs);
    } else {
        int r = bid - 256;
        int z = r >> 3, x = r & 7;
        gemm_nn_body<false>(sbuf + (size_t)z*Tdim*Tdim, Tdim,
                            dec + (size_t)z*Tdim*Hdim, Hdim,
                            cat + (size_t)z*Tdim*CATdim + 2*Hdim, nullptr, CATdim,
                            Tdim, Hdim, Tdim, 0, x*64, As, Bs);
    }
}

// ============ launch E: proj GEMM (K=1536) with fused bf16 epilogue =======
__global__ __launch_bounds__(256) void kE(
    const float* __restrict__ cat, const float* __restrict__ Wproj,
    short* __restrict__ projb)
{
    __shared__ float As[16][68];
    __shared__ float Bs[16][68];
    int by = blockIdx.x >> 1, bx = blockIdx.x & 1;
    gemm_nn_body<true>(cat, CATdim, Wproj, Edim,
                       nullptr, projb, Edim,
                       BTdim, Edim, CATdim, by*64, bx*64, As, Bs);
}

// ============ launch F: logits pass 1 — atomic per-row exp-sums ===========
// Swapped-operand 16x16x32 MFMA: m is lane-local (lane&15); 64-col sum needs
// only 2 shfl_xor stages; lane<16 atomicAdd into sums[m]. mt range split
// over blockIdx.y for occupancy.
__global__ __launch_bounds__(256) void kF(
    const short* __restrict__ Ab, const short* __restrict__ Bt,
    float* __restrict__ sums)
{
    const int lane = threadIdx.x & 63;
    const int wave = threadIdx.x >> 6;
    const int l15 = lane & 15, quad = lane >> 4;
    const int wid = blockIdx.x*4 + wave;
    if (wid >= NPART) return;
    const int n0 = wid*64;
    short8 bfrag[4][4];
    #pragma unroll
    for (int ct=0;ct<4;ct++){
        const short* bp = Bt + (size_t)(n0 + ct*16 + l15)*Edim + quad*8;
        #pragma unroll
        for (int kk=0;kk<4;kk++) bfrag[ct][kk] = *(const short8*)(bp + kk*32);
    }
    float vmask[4];
    #pragma unroll
    for (int ct=0;ct<4;ct++) vmask[ct] = (n0 + ct*16 < Vdim) ? 1.f : 0.f;

    auto loadA = [&](int mt, short8 (&af)[4]){
        const short* ap = Ab + (size_t)(mt*16 + l15)*Edim + quad*8;
        #pragma unroll
        for (int kk=0;kk<4;kk++) af[kk] = *(const short8*)(ap + kk*32);
    };
    auto compute = [&](int mt, short8 (&af)[4]){
        floatx4 a0 = {0.f,0.f,0.f,0.f};
        floatx4 a1 = a0, a2 = a0, a3 = a0;
        #pragma unroll
        for (int kk=0;kk<4;kk++){
            a0 = __builtin_amdgcn_mfma_f32_16x16x32_bf16(bfrag[0][kk], af[kk], a0, 0, 0, 0);
            a1 = __builtin_amdgcn_mfma_f32_16x16x32_bf16(bfrag[1][kk], af[kk], a1, 0, 0, 0);
            a2 = __builtin_amdgcn_mfma_f32_16x16x32_bf16(bfrag[2][kk], af[kk], a2, 0, 0, 0);
            a3 = __builtin_amdgcn_mfma_f32_16x16x32_bf16(bfrag[3][kk], af[kk], a3, 0, 0, 0);
        }
        float s = vmask[0]*(__expf(a0[0])+__expf(a0[1])+__expf(a0[2])+__expf(a0[3]))
                + vmask[1]*(__expf(a1[0])+__expf(a1[1])+__expf(a1[2])+__expf(a1[3]))
                + vmask[2]*(__expf(a2[0])+__expf(a2[1])+__expf(a2[2])+__expf(a2[3]))
                + vmask[3]*(__expf(a3[0])+__expf(a3[1])+__expf(a3[2])+__expf(a3[3]));
        s += __shfl_xor(s, 16, 64);
        s += __shfl_xor(s, 32, 64);
        if (lane < 16)
            atomicAdd(&sums[mt*16 + l15], s);
    };

    const int mt0 = blockIdx.y*48, mt1 = mt0 + 48;
    short8 afA[4], afB[4];
    loadA(mt0, afA);
    for (int mt=mt0; mt<mt1; mt+=2){
        loadA(mt+1, afB);
        compute(mt, afA);
        if (mt+2 < mt1) loadA(mt+2, afA);
        compute(mt+1, afB);
    }
}

// ============ launch G: logits pass 2 + fused pointer scatter ==============
// Block (x,y) owns rows [y*768, y*768+768) x cols [x*128, x*128+128).
// After its stores, it scans ev for hits in its column range and does the
// scatter-adds itself (intra-block ordering via __syncthreads; same-L2
// visibility since store and atomic are same-CU).
__global__ __launch_bounds__(256) void kG(
    const short* __restrict__ Ab, const short* __restrict__ Bt,
    const float* __restrict__ sums, const float* __restrict__ pg,
    const float* __restrict__ att, const int* __restrict__ ev,
    float* __restrict__ out)
{
    __shared__ float scl[768];
    __shared__ int hits[6400];
    __shared__ int hcnt;
    const int lane = threadIdx.x & 63;
    const int wave = threadIdx.x >> 6;
    const int l31 = lane & 31, half = lane >> 5;
    const int n0 = blockIdx.x*128 + wave*32;
    const int n = n0 + l31;
    const int yoff = blockIdx.y*768;
    const int mt0 = blockIdx.y*24;
    for (int i = threadIdx.x; i < 768; i += 256){
        int m = yoff + i;
        scl[i] = (1.f - pg[m]) / sums[m];
    }
    if (threadIdx.x == 0) hcnt = 0;
    __syncthreads();

    if (n0 >= Vdim){
        if (n < VEdim){
            for (int mt=mt0; mt<mt0+24; ++mt){
                #pragma unroll
                for (int r=0;r<16;r++){
                    int m = mt*32 + (r&3) + 8*(r>>2) + 4*half;
                    out[(size_t)m*VEdim + n] = 0.f;
                }
            }
        }
    } else {
        short8 bfrag[8];
        const short* bp = Bt + (size_t)n*Edim + half*8;
        #pragma unroll
        for (int kk=0;kk<8;kk++) bfrag[kk] = *(const short8*)(bp + kk*16);
        const bool valid = n < Vdim;
        for (int mt=mt0; mt<mt0+24; ++mt){
            floatx16 acc;
            #pragma unroll
            for (int i=0;i<16;i++) acc[i] = 0.f;
            const short* ap = Ab + (size_t)(mt*32 + l31)*Edim + half*8;
            #pragma unroll
            for (int kk=0;kk<8;kk++){
                short8 af = *(const short8*)(ap + kk*16);
                acc = __builtin_amdgcn_mfma_f32_32x32x16_bf16(af, bfrag[kk], acc, 0, 0, 0);
            }
            #pragma unroll
            for (int r=0;r<16;r++){
                int m = mt*32 + (r&3) + 8*(r>>2) + 4*half;
                if (valid) out[(size_t)m*VEdim + n] = scl[m - yoff]*__expf(acc[r]);
                else if (n < VEdim) out[(size_t)m*VEdim + n] = 0.f;
            }
        }
    }
    // -------- fused scatter: find ev hits in this block's column range ----
    for (int idx = threadIdx.x; idx < 16*Ldim; idx += 256){
        int b = (blockIdx.y << 4) + idx/Ldim;
        int l = idx % Ldim;
        int v = ev[b*Ldim + l];
        if ((v >> 7) == (int)blockIdx.x){
            int h = atomicAdd(&hcnt, 1);
            hits[h] = (v << 14) | ((b & 31) << 9) | l;
        }
    }
    __syncthreads();
    const int tot = hcnt * Tdim;
    for (int j = threadIdx.x; j < tot; j += 256){
        int h = j / Tdim, t = j % Tdim;
        int pk = hits[h];
        int v = pk >> 14;
        int b = (pk >> 9) & 31;
        int l = pk & 511;
        int m = b*Tdim + t;
        atomicAdd(&out[(size_t)m*VEdim + v], pg[m]*att[(size_t)m*Ldim + l]);
    }
}

extern "C" void kernel_launch(void* const* d_in, const int* in_sizes, int n_in,
                              void* d_out, int out_size, void* d_ws, size_t ws_size,
                              hipStream_t stream)
{
    const float* dec  = (const float*)d_in[0];
    const float* enc  = (const float*)d_in[1];
    const float* Wenc = (const float*)d_in[2];
    const float* Wdec = (const float*)d_in[3];
    const float* Wproj= (const float*)d_in[4];
    const float* Wvoc = (const float*)d_in[5];
    const float* wptr = (const float*)d_in[6];
    const float* bptr = (const float*)d_in[7];
    const int*   ev   = (const int*)d_in[8];
    float* out = (float*)d_out;

    float* ws = (float*)d_ws;
    float* P1    = ws;                   // 1536x512
    float* P2    = P1 + 786432;          // 1536x512
    float* ebuf  = P2 + 786432;          // 32x48x400
    float* att   = ebuf + 614400;        // 32x48x400
    float* sbuf  = att + 614400;         // 32x48x48
    float* cat   = sbuf + 73728;         // 1536x1536
    float* q_enc = cat + 2359296;        // 32x400
    float* q_dec = q_enc + 12800;        // 32x48
    float* pg    = q_dec + 1536;         // 1536
    float* sums  = pg + 1536;            // 1536
    short* projb = (short*)(sums + 1536);    // 1536x128 bf16
    short* Wt    = projb + 196608;           // 50048x128 bf16

    dim3 blk(256);
    // A: p12 GEMMs (384) + h-copy (768) + Wv transpose (6256) + qenc/qdec (128)
    //    + zero sums (1)
    kA<<<dim3(7537), blk, 0, stream>>>(dec, Wenc, Wdec, P1, P2, cat,
                                       Wvoc, Wt, enc, wptr, q_enc, q_dec, sums);
    // B: e-scores (224) + s-scores (32)
    kB<<<dim3(256), blk, 0, stream>>>(P1, P2, enc, dec, ebuf, sbuf);
    // C: temporal scan + normalize + decoder softmax + pgate (per b)
    kC<<<dim3(Bdim), dim3(512), 0, stream>>>(ebuf, att, sbuf, dec, wptr, bptr,
                                             q_enc, q_dec, pg);
    // D: enc_ctx (256) + dec_ctx (256) GEMMs
    kD<<<dim3(512), blk, 0, stream>>>(att, sbuf, enc, dec, cat);
    // E: proj GEMM with bf16 epilogue
    kE<<<dim3(48), blk, 0, stream>>>(cat, Wproj, projb);
    // F: logits pass 1 (atomic row sums)
    kF<<<dim3(196,2), blk, 0, stream>>>(projb, Wt, sums);
    // G: logits pass 2 + fused scatter
    kG<<<dim3(392,2), blk, 0, stream>>>(projb, Wt, sums, pg, att, ev, out);
}

// Round 3
// 696.473 us; speedup vs baseline: 1.0724x; 1.0724x over previous
//
#include <hip/hip_runtime.h>
#include <hip/hip_bf16.h>
#include <cstdint>

typedef __attribute__((ext_vector_type(8))) short short8;
typedef __attribute__((ext_vector_type(4))) float floatx4;
typedef __attribute__((ext_vector_type(16))) float floatx16;

#define Bdim 32
#define Tdim 48
#define Ldim 400
#define Hdim 512
#define Edim 128
#define Vdim 50000
#define VEdim 50100
#define BTdim 1536
#define CATdim 1536
#define NPAD 50048     // 782*64; also 391*128
#define MTILES 96      // BTdim/16
#define NPART 782      // 64-col tiles in pass 1
#define NPSTRIDE 800   // padded row stride of partial[m][wid]

__device__ __forceinline__ short f2bf(float x){
    __hip_bfloat16 h = __float2bfloat16(x);
    union { __hip_bfloat16 h; short s; } u; u.h = h; return u.s;
}

__device__ __forceinline__ float wred(float s){
    #pragma unroll
    for (int off = 32; off; off >>= 1) s += __shfl_xor(s, off, 64);
    return s;
}

// ---------------- fp32 tiled GEMM body, C = A(MxK) @ B(KxN), row-major ----
// register double-buffer prefetch; optional bf16 output (template).
template<bool BF16>
__device__ __forceinline__ void gemm_nn_body(
    const float* __restrict__ A, int lda,
    const float* __restrict__ B, int ldb,
    float* __restrict__ C, short* __restrict__ Cb, int ldc,
    int M, int N, int K, int m0, int n0,
    float (*As)[68], float (*Bs)[68])
{
    const int tid = threadIdx.x;
    const int tx = tid & 15, ty = tid >> 4;
    const int ar = tid >> 2, ac = (tid & 3) * 4;   // A: row in tile, col*4
    const int br = tid >> 4, bc = (tid & 15) * 4;  // B: row in tile, col*4
    float acc[4][4] = {};
    float4 va = make_float4(0.f,0.f,0.f,0.f);
    float4 vb = make_float4(0.f,0.f,0.f,0.f);
    if (m0 + ar < M) va = *(const float4*)(A + (size_t)(m0+ar)*lda + ac);
    if (n0 + bc < N) vb = *(const float4*)(B + (size_t)br*ldb + n0 + bc);
    for (int k0 = 0; k0 < K; k0 += 16){
        As[ac+0][ar]=va.x; As[ac+1][ar]=va.y; As[ac+2][ar]=va.z; As[ac+3][ar]=va.w;
        Bs[br][bc+0]=vb.x; Bs[br][bc+1]=vb.y; Bs[br][bc+2]=vb.z; Bs[br][bc+3]=vb.w;
        __syncthreads();
        const int kn = k0 + 16;
        if (kn < K){
            va = make_float4(0.f,0.f,0.f,0.f);
            vb = make_float4(0.f,0.f,0.f,0.f);
            if (m0 + ar < M) va = *(const float4*)(A + (size_t)(m0+ar)*lda + kn + ac);
            if (n0 + bc < N) vb = *(const float4*)(B + (size_t)(kn+br)*ldb + n0 + bc);
        }
        #pragma unroll
        for (int k=0;k<16;k++){
            float a[4], b[4];
            #pragma unroll
            for (int i=0;i<4;i++) a[i] = As[k][ty*4+i];
            #pragma unroll
            for (int j=0;j<4;j++) b[j] = Bs[k][tx*4+j];
            #pragma unroll
            for (int i=0;i<4;i++)
                #pragma unroll
                for (int j=0;j<4;j++)
                    acc[i][j] += a[i]*b[j];
        }
        __syncthreads();
    }
    #pragma unroll
    for (int i=0;i<4;i++){
        int m = m0 + ty*4 + i;
        if (m >= M) continue;
        #pragma unroll
        for (int j=0;j<4;j++){
            int n = n0 + tx*4 + j;
            if (n < N){
                if (BF16) Cb[(size_t)m*ldc + n] = f2bf(acc[i][j]);
                else      C[(size_t)m*ldc + n]  = acc[i][j];
            }
        }
    }
}

// ---------------- fp32 tiled GEMM body, C = A(MxK) @ B(NxK)^T -------------
__device__ __forceinline__ void gemm_nt_body(
    const float* __restrict__ A, int lda,
    const float* __restrict__ B, int ldb,
    float* __restrict__ C, int ldc,
    int M, int N, int K, int m0, int n0,
    float (*As)[68], float (*Bs)[68])
{
    const int tid = threadIdx.x;
    const int tx = tid & 15, ty = tid >> 4;
    const int r = tid >> 2, c = (tid & 3) * 4;
    float acc[4][4] = {};
    float4 va = make_float4(0.f,0.f,0.f,0.f);
    float4 vb = make_float4(0.f,0.f,0.f,0.f);
    if (m0 + r < M) va = *(const float4*)(A + (size_t)(m0+r)*lda + c);
    if (n0 + r < N) vb = *(const float4*)(B + (size_t)(n0+r)*ldb + c);
    for (int k0 = 0; k0 < K; k0 += 16){
        As[c+0][r]=va.x; As[c+1][r]=va.y; As[c+2][r]=va.z; As[c+3][r]=va.w;
        Bs[c+0][r]=vb.x; Bs[c+1][r]=vb.y; Bs[c+2][r]=vb.z; Bs[c+3][r]=vb.w;
        __syncthreads();
        const int kn = k0 + 16;
        if (kn < K){
            va = make_float4(0.f,0.f,0.f,0.f);
            vb = make_float4(0.f,0.f,0.f,0.f);
            if (m0 + r < M) va = *(const float4*)(A + (size_t)(m0+r)*lda + kn + c);
            if (n0 + r < N) vb = *(const float4*)(B + (size_t)(n0+r)*ldb + kn + c);
        }
        #pragma unroll
        for (int k=0;k<16;k++){
            float a[4], b[4];
            #pragma unroll
            for (int i=0;i<4;i++) a[i] = As[k][ty*4+i];
            #pragma unroll
            for (int j=0;j<4;j++) b[j] = Bs[k][tx*4+j];
            #pragma unroll
            for (int i=0;i<4;i++)
                #pragma unroll
                for (int j=0;j<4;j++)
                    acc[i][j] += a[i]*b[j];
        }
        __syncthreads();
    }
    #pragma unroll
    for (int i=0;i<4;i++){
        int m = m0 + ty*4 + i;
        if (m >= M) continue;
        #pragma unroll
        for (int j=0;j<4;j++){
            int n = n0 + tx*4 + j;
            if (n < N) C[(size_t)m*ldc + n] = acc[i][j];
        }
    }
}

// ============ launch A: p12 GEMMs + h-copy(bf16) + Wv transpose +
//              Wproj transpose(bf16) + q_enc/q_dec ========================
__global__ __launch_bounds__(256) void kA(
    const float* __restrict__ dec, const float* __restrict__ Wenc,
    const float* __restrict__ Wdec, float* __restrict__ P1, float* __restrict__ P2,
    short* __restrict__ catb,
    const float* __restrict__ Wv, short* __restrict__ Wt,
    const float* __restrict__ Wproj, short* __restrict__ WpT,
    const float* __restrict__ enc, const float* __restrict__ wptr,
    float* __restrict__ q_enc, float* __restrict__ q_dec)
{
    __shared__ float As[16][68];
    __shared__ float Bs[16][68];
    int bid = blockIdx.x;
    if (bid < 384){
        int z = bid / 192, r = bid % 192;
        gemm_nn_body<false>(dec, Hdim, z ? Wdec : Wenc, Hdim,
                            z ? P2 : P1, nullptr, Hdim,
                            BTdim, Hdim, Hdim, (r>>3)*64, (r&7)*64, As, Bs);
        return;
    }
    bid -= 384;
    if (bid < 384){
        // copy h into catb[:, 0:512] as bf16; 8 elems/thread
        int idx = bid*256 + threadIdx.x;          // 0..98303
        int m = idx >> 6, j = (idx & 63) << 3;
        float4 v0 = *(const float4*)(dec + (size_t)m*Hdim + j);
        float4 v1 = *(const float4*)(dec + (size_t)m*Hdim + j + 4);
        short8 s;
        s[0]=f2bf(v0.x); s[1]=f2bf(v0.y); s[2]=f2bf(v0.z); s[3]=f2bf(v0.w);
        s[4]=f2bf(v1.x); s[5]=f2bf(v1.y); s[6]=f2bf(v1.z); s[7]=f2bf(v1.w);
        *(short8*)(catb + (size_t)m*CATdim + j) = s;
        return;
    }
    bid -= 384;
    if (bid < 6256){
        // W_vocab (128 x 50000) -> bf16 transposed (50048 x 128)
        float (*tile)[33] = reinterpret_cast<float(*)[33]>(&As[0][0]);  // 1056<=1088
        int n0 = (bid % 1564)*32, k0 = (bid / 1564)*32;
        int x = threadIdx.x & 31, y0 = threadIdx.x >> 5;  // 32 x 8
        for (int yy=y0; yy<32; yy+=8){
            int n = n0 + x;
            tile[yy][x] = (n < Vdim) ? Wv[(size_t)(k0+yy)*Vdim + n] : 0.f;
        }
        __syncthreads();
        for (int yy=y0; yy<32; yy+=8){
            int n = n0 + yy;
            if (n < NPAD) Wt[(size_t)n*Edim + k0 + x] = f2bf(tile[x][yy]);
        }
        return;
    }
    bid -= 6256;
    if (bid < 192){
        // Wproj (1536 x 128) -> bf16 transposed WpT (128 x 1536)
        float (*tile)[33] = reinterpret_cast<float(*)[33]>(&As[0][0]);
        int k0 = (bid / 4)*32, n0 = (bid % 4)*32;
        int x = threadIdx.x & 31, y0 = threadIdx.x >> 5;
        for (int yy=y0; yy<32; yy+=8)
            tile[yy][x] = Wproj[(size_t)(k0+yy)*Edim + n0 + x];
        __syncthreads();
        for (int yy=y0; yy<32; yy+=8)
            WpT[(size_t)(n0+yy)*CATdim + k0 + x] = f2bf(tile[x][yy]);
        return;
    }
    bid -= 192;
    {
        // q_enc[b][l] = enc[b][l] . w2 ; q_dec[b][t] = dec[b][t] . w3
        int b = bid >> 2, part = bid & 3;
        int wv = threadIdx.x >> 6, lane = threadIdx.x & 63;
        const float* w2 = wptr + Hdim;
        const float* w3 = wptr + 2*Hdim;
        for (int r = part*100 + wv; r < part*100 + 100; r += 4){
            const float* rp = enc + ((size_t)b*Ldim + r)*Hdim;
            float s = 0.f;
            #pragma unroll
            for (int i = 0; i < 8; i++) s += rp[lane + i*64]*w2[lane + i*64];
            s = wred(s);
            if (lane == 0) q_enc[b*Ldim + r] = s;
        }
        if (part == 0){
            for (int r = wv; r < Tdim; r += 4){
                const float* rp = dec + ((size_t)b*Tdim + r)*Hdim;
                float s = 0.f;
                #pragma unroll
                for (int i = 0; i < 8; i++) s += rp[lane + i*64]*w3[lane + i*64];
                s = wred(s);
                if (lane == 0) q_dec[b*Tdim + r] = s;
            }
        }
    }
}

// ============ launch B: e-scores + s-scores (NT GEMMs) ====================
__global__ __launch_bounds__(256) void kB(
    const float* __restrict__ P1, const float* __restrict__ P2,
    const float* __restrict__ enc, const float* __restrict__ dec,
    float* __restrict__ ebuf, float* __restrict__ sbuf)
{
    __shared__ float As[16][68];
    __shared__ float Bs[16][68];
    int bid = blockIdx.x;
    if (bid < 224){
        int z = bid / 7, x = bid % 7;
        gemm_nt_body(P1 + (size_t)z*Tdim*Hdim, Hdim,
                     enc + (size_t)z*Ldim*Hdim, Hdim,
                     ebuf + (size_t)z*Tdim*Ldim, Ldim,
                     Tdim, Ldim, Hdim, 0, x*64, As, Bs);
    } else {
        int z = bid - 224;
        gemm_nt_body(P2 + (size_t)z*Tdim*Hdim, Hdim,
                     dec + (size_t)z*Tdim*Hdim, Hdim,
                     sbuf + (size_t)z*Tdim*Tdim, Tdim,
                     Tdim, Tdim, Hdim, 0, 0, As, Bs);
    }
}

// ============ launch C: per-b temporal scan + l-normalize + masked decoder
//              softmax + pointer gate. 32 blocks x 512 threads. =============
__global__ __launch_bounds__(512) void kC(
    const float* __restrict__ e, float* __restrict__ att, float* __restrict__ sbuf,
    const float* __restrict__ dec, const float* __restrict__ wptr,
    const float* __restrict__ bptr,
    const float* __restrict__ q_enc, const float* __restrict__ q_dec,
    float* __restrict__ pg)
{
    __shared__ float att_s[Tdim][Ldim];   // 75 KB
    __shared__ float dE[Tdim], dD[Tdim], dH[Tdim];
    const int b = blockIdx.x;
    const int tid = threadIdx.x;
    // temporal prefix scan over t (one thread per l)
    if (tid < Ldim){
        const float* ep = e + (size_t)b*Tdim*Ldim + tid;
        float acc = 0.f;
        for (int t = 0; t < Tdim; ++t){
            float x = __expf(ep[t*Ldim]);
            att_s[t][tid] = x / (t ? acc : 1.f);
            acc += x;
        }
    }
    __syncthreads();
    const int wv = tid >> 6, lane = tid & 63;
    // per-row normalize + dot with q_enc; write normalized att to global
    for (int t = wv; t < Tdim; t += 8){
        float s1 = 0.f, s2 = 0.f;
        for (int l = lane; l < Ldim; l += 64){
            float a = att_s[t][l];
            s1 += a;
            s2 += a * q_enc[b*Ldim + l];
        }
        s1 = wred(s1); s2 = wred(s2);
        float inv = 1.f/s1;
        if (lane == 0) dE[t] = s2*inv;
        for (int l = lane; l < Ldim; l += 64)
            att[(size_t)(b*Tdim + t)*Ldim + l] = att_s[t][l]*inv;
    }
    // h . w1 per row
    for (int t = wv; t < Tdim; t += 8){
        const float* hp = dec + ((size_t)b*Tdim + t)*Hdim;
        float s = 0.f;
        #pragma unroll
        for (int i = 0; i < 8; i++) s += hp[lane + i*64]*wptr[lane + i*64];
        s = wred(s);
        if (lane == 0) dH[t] = s;
    }
    // masked decoder softmax per row + dot with q_dec
    for (int t = wv; t < Tdim; t += 8){
        float* row = sbuf + ((size_t)b*Tdim + t)*Tdim;
        if (t == 0){
            if (lane < Tdim) row[lane] = 0.f;
            if (lane == 0) dD[0] = 0.f;
        } else {
            float v = (lane < t) ? row[lane] : -1e30f;
            float mx = v;
            #pragma unroll
            for (int off = 32; off; off >>= 1) mx = fmaxf(mx, __shfl_xor(mx, off, 64));
            float ex = (lane < t) ? __expf(v - mx) : 0.f;
            float sm = wred(ex);
            float nv = ex / sm;
            if (lane < Tdim) row[lane] = nv;
            float d = (lane < Tdim) ? nv * q_dec[b*Tdim + lane] : 0.f;
            d = wred(d);
            if (lane == 0) dD[t] = d;
        }
    }
    __syncthreads();
    if (tid < Tdim){
        float tot = dH[tid] + dE[tid] + dD[tid] + bptr[0];
        pg[b*Tdim + tid] = 1.f/(1.f + __expf(-tot));
    }
}

// ============ launch D: enc_ctx + dec_ctx GEMMs into catb (bf16) ==========
__global__ __launch_bounds__(256) void kD(
    const float* __restrict__ att, const float* __restrict__ sbuf,
    const float* __restrict__ enc, const float* __restrict__ dec,
    short* __restrict__ catb)
{
    __shared__ float As[16][68];
    __shared__ float Bs[16][68];
    int bid = blockIdx.x;
    if (bid < 256){
        int z = bid >> 3, x = bid & 7;
        gemm_nn_body<true>(att + (size_t)z*Tdim*Ldim, Ldim,
                           enc + (size_t)z*Ldim*Hdim, Hdim,
                           nullptr, catb + (size_t)z*Tdim*CATdim + Hdim, CATdim,
                           Tdim, Hdim, Ldim, 0, x*64, As, Bs);
    } else {
        int r = bid - 256;
        int z = r >> 3, x = r & 7;
        gemm_nn_body<true>(sbuf + (size_t)z*Tdim*Tdim, Tdim,
                           dec + (size_t)z*Tdim*Hdim, Hdim,
                           nullptr, catb + (size_t)z*Tdim*CATdim + 2*Hdim, CATdim,
                           Tdim, Hdim, Tdim, 0, x*64, As, Bs);
    }
}

// ============ launch E: proj GEMM via bf16 MFMA ===========================
// projb[m][n] = sum_k catb[m][k]*WpT[n][k]; block = one 32-row tile of m,
// 4 waves cover n = 0..127. Same operand/C-layout pattern as kG (verified).
__global__ __launch_bounds__(256) void kE(
    const short* __restrict__ catb, const short* __restrict__ WpT,
    short* __restrict__ projb)
{
    const int lane = threadIdx.x & 63;
    const int wave = threadIdx.x >> 6;
    const int l31 = lane & 31, half = lane >> 5;
    const int mt = blockIdx.x;           // 0..47
    const int n0 = wave*32;
    const short* ap = catb + (size_t)(mt*32 + l31)*CATdim + half*8;
    const short* bp = WpT  + (size_t)(n0 + l31)*CATdim + half*8;
    floatx16 acc;
    #pragma unroll
    for (int i=0;i<16;i++) acc[i] = 0.f;
    #pragma unroll 4
    for (int kk=0;kk<96;kk++){
        short8 af = *(const short8*)(ap + kk*16);
        short8 bf = *(const short8*)(bp + kk*16);
        acc = __builtin_amdgcn_mfma_f32_32x32x16_bf16(af, bf, acc, 0, 0, 0);
    }
    #pragma unroll
    for (int r=0;r<16;r++){
        int m = mt*32 + (r&3) + 8*(r>>2) + 4*half;
        projb[(size_t)m*Edim + n0 + l31] = f2bf(acc[r]);
    }
}

// ============ launch F: logits pass 1 — per-row exp-sum partials ==========
// Swapped-operand 16x16x32 MFMA: m is lane-local (lane&15); 64-col sum needs
// only 2 shfl_xor stages; lane<16 stores to partial[m][wid] (stride 800) so
// kRed reads coalesced rows. 2-deep A-fragment prefetch.
__global__ __launch_bounds__(256) void kF(
    const short* __restrict__ Ab, const short* __restrict__ Bt,
    float* __restrict__ partial)
{
    const int lane = threadIdx.x & 63;
    const int wave = threadIdx.x >> 6;
    const int l15 = lane & 15, quad = lane >> 4;
    const int wid = blockIdx.x*4 + wave;
    if (wid >= NPART) return;
    const int n0 = wid*64;
    short8 bfrag[4][4];
    #pragma unroll
    for (int ct=0;ct<4;ct++){
        const short* bp = Bt + (size_t)(n0 + ct*16 + l15)*Edim + quad*8;
        #pragma unroll
        for (int kk=0;kk<4;kk++) bfrag[ct][kk] = *(const short8*)(bp + kk*32);
    }
    float vmask[4];
    #pragma unroll
    for (int ct=0;ct<4;ct++) vmask[ct] = (n0 + ct*16 < Vdim) ? 1.f : 0.f;

    auto loadA = [&](int mt, short8 (&af)[4]){
        const short* ap = Ab + (size_t)(mt*16 + l15)*Edim + quad*8;
        #pragma unroll
        for (int kk=0;kk<4;kk++) af[kk] = *(const short8*)(ap + kk*32);
    };
    auto compute = [&](int mt, short8 (&af)[4]){
        floatx4 a0 = {0.f,0.f,0.f,0.f};
        floatx4 a1 = a0, a2 = a0, a3 = a0;
        #pragma unroll
        for (int kk=0;kk<4;kk++){
            a0 = __builtin_amdgcn_mfma_f32_16x16x32_bf16(bfrag[0][kk], af[kk], a0, 0, 0, 0);
            a1 = __builtin_amdgcn_mfma_f32_16x16x32_bf16(bfrag[1][kk], af[kk], a1, 0, 0, 0);
            a2 = __builtin_amdgcn_mfma_f32_16x16x32_bf16(bfrag[2][kk], af[kk], a2, 0, 0, 0);
            a3 = __builtin_amdgcn_mfma_f32_16x16x32_bf16(bfrag[3][kk], af[kk], a3, 0, 0, 0);
        }
        float s = vmask[0]*(__expf(a0[0])+__expf(a0[1])+__expf(a0[2])+__expf(a0[3]))
                + vmask[1]*(__expf(a1[0])+__expf(a1[1])+__expf(a1[2])+__expf(a1[3]))
                + vmask[2]*(__expf(a2[0])+__expf(a2[1])+__expf(a2[2])+__expf(a2[3]))
                + vmask[3]*(__expf(a3[0])+__expf(a3[1])+__expf(a3[2])+__expf(a3[3]));
        s += __shfl_xor(s, 16, 64);
        s += __shfl_xor(s, 32, 64);
        if (lane < 16)
            partial[(size_t)(mt*16 + l15)*NPSTRIDE + wid] = s;
    };

    short8 afA[4], afB[4];
    loadA(0, afA);
    for (int mt=0; mt<MTILES; mt+=2){
        loadA(mt+1, afB);
        compute(mt, afA);
        if (mt+2 < MTILES) loadA(mt+2, afA);
        compute(mt+1, afB);
    }
}

// ============ launch R: reduce partials -> scale = (1-p)/S ================
__global__ __launch_bounds__(256) void kRed(const float* __restrict__ partial,
                         const float* __restrict__ pg, float* __restrict__ scale){
    int m = blockIdx.x;
    float s = 0.f;
    for (int w = threadIdx.x; w < NPART; w += 256)
        s += partial[(size_t)m*NPSTRIDE + w];
    #pragma unroll
    for (int off=32; off; off>>=1) s += __shfl_down(s, off, 64);
    __shared__ float red[4];
    if ((threadIdx.x&63)==0) red[threadIdx.x>>6]=s;
    __syncthreads();
    if (threadIdx.x==0)
        scale[m] = (1.f - pg[m]) / (red[0]+red[1]+red[2]+red[3]);
}

// ============ launch G: logits pass 2 + fused pointer scatter ==============
// Block (x,y) owns rows [y*768, y*768+768) x cols [x*128, x*128+128).
// __syncthreads drains vmcnt -> stores complete before the block's own
// scatter atomics to the same region (same-CU, same-L2).
__global__ __launch_bounds__(256) void kG(
    const short* __restrict__ Ab, const short* __restrict__ Bt,
    const float* __restrict__ scale, const float* __restrict__ pg,
    const float* __restrict__ att, const int* __restrict__ ev,
    float* __restrict__ out)
{
    __shared__ float scl[768];
    __shared__ int hits[6400];
    __shared__ int hcnt;
    const int lane = threadIdx.x & 63;
    const int wave = threadIdx.x >> 6;
    const int l31 = lane & 31, half = lane >> 5;
    const int n0 = blockIdx.x*128 + wave*32;
    const int n = n0 + l31;
    const int yoff = blockIdx.y*768;
    const int mt0 = blockIdx.y*24;
    for (int i = threadIdx.x; i < 768; i += 256)
        scl[i] = scale[yoff + i];
    if (threadIdx.x == 0) hcnt = 0;
    __syncthreads();

    if (n0 >= Vdim){
        if (n < VEdim){
            for (int mt=mt0; mt<mt0+24; ++mt){
                #pragma unroll
                for (int r=0;r<16;r++){
                    int m = mt*32 + (r&3) + 8*(r>>2) + 4*half;
                    out[(size_t)m*VEdim + n] = 0.f;
                }
            }
        }
    } else {
        short8 bfrag[8];
        const short* bp = Bt + (size_t)n*Edim + half*8;
        #pragma unroll
        for (int kk=0;kk<8;kk++) bfrag[kk] = *(const short8*)(bp + kk*16);
        const bool valid = n < Vdim;
        for (int mt=mt0; mt<mt0+24; ++mt){
            floatx16 acc;
            #pragma unroll
            for (int i=0;i<16;i++) acc[i] = 0.f;
            const short* ap = Ab + (size_t)(mt*32 + l31)*Edim + half*8;
            #pragma unroll
            for (int kk=0;kk<8;kk++){
                short8 af = *(const short8*)(ap + kk*16);
                acc = __builtin_amdgcn_mfma_f32_32x32x16_bf16(af, bfrag[kk], acc, 0, 0, 0);
            }
            #pragma unroll
            for (int r=0;r<16;r++){
                int m = mt*32 + (r&3) + 8*(r>>2) + 4*half;
                if (valid) out[(size_t)m*VEdim + n] = scl[m - yoff]*__expf(acc[r]);
                else if (n < VEdim) out[(size_t)m*VEdim + n] = 0.f;
            }
        }
    }
    // -------- fused scatter: find ev hits in this block's column range ----
    for (int idx = threadIdx.x; idx < 16*Ldim; idx += 256){
        int b = (blockIdx.y << 4) + idx/Ldim;
        int l = idx % Ldim;
        int v = ev[b*Ldim + l];
        if ((v >> 7) == (int)blockIdx.x){
            int h = atomicAdd(&hcnt, 1);
            hits[h] = (v << 14) | ((b & 31) << 9) | l;
        }
    }
    __syncthreads();
    const int tot = hcnt * Tdim;
    for (int j = threadIdx.x; j < tot; j += 256){
        int h = j / Tdim, t = j % Tdim;
        int pk = hits[h];
        int v = pk >> 14;
        int b = (pk >> 9) & 31;
        int l = pk & 511;
        int m = b*Tdim + t;
        atomicAdd(&out[(size_t)m*VEdim + v], pg[m]*att[(size_t)m*Ldim + l]);
    }
}

extern "C" void kernel_launch(void* const* d_in, const int* in_sizes, int n_in,
                              void* d_out, int out_size, void* d_ws, size_t ws_size,
                              hipStream_t stream)
{
    const float* dec  = (const float*)d_in[0];
    const float* enc  = (const float*)d_in[1];
    const float* Wenc = (const float*)d_in[2];
    const float* Wdec = (const float*)d_in[3];
    const float* Wproj= (const float*)d_in[4];
    const float* Wvoc = (const float*)d_in[5];
    const float* wptr = (const float*)d_in[6];
    const float* bptr = (const float*)d_in[7];
    const int*   ev   = (const int*)d_in[8];
    float* out = (float*)d_out;

    float* ws = (float*)d_ws;
    float* P1    = ws;                   // 1536x512
    float* P2    = P1 + 786432;          // 1536x512
    float* ebuf  = P2 + 786432;          // 32x48x400
    float* att   = ebuf + 614400;        // 32x48x400
    float* sbuf  = att + 614400;         // 32x48x48
    float* q_enc = sbuf + 73728;         // 32x400
    float* q_dec = q_enc + 12800;        // 32x48
    float* pg    = q_dec + 1536;         // 1536
    float* scale = pg + 1536;            // 1536
    float* partial = scale + 1536;       // 1536 x 800
    short* catb  = (short*)(partial + (size_t)BTdim*NPSTRIDE);  // 1536x1536 bf16
    short* projb = catb + (size_t)BTdim*CATdim;   // 1536x128 bf16
    short* WpT   = projb + 196608;                // 128x1536 bf16
    short* Wt    = WpT + 196608;                  // 50048x128 bf16

    dim3 blk(256);
    // A: p12 GEMMs (384) + h->catb (384) + Wv transpose (6256)
    //    + Wproj transpose (192) + qenc/qdec (128)
    kA<<<dim3(7344), blk, 0, stream>>>(dec, Wenc, Wdec, P1, P2, catb,
                                       Wvoc, Wt, Wproj, WpT, enc, wptr,
                                       q_enc, q_dec);
    // B: e-scores (224) + s-scores (32)
    kB<<<dim3(256), blk, 0, stream>>>(P1, P2, enc, dec, ebuf, sbuf);
    // C: temporal scan + normalize + decoder softmax + pgate (per b)
    kC<<<dim3(Bdim), dim3(512), 0, stream>>>(ebuf, att, sbuf, dec, wptr, bptr,
                                             q_enc, q_dec, pg);
    // D: enc_ctx (256) + dec_ctx (256) GEMMs -> catb
    kD<<<dim3(512), blk, 0, stream>>>(att, sbuf, enc, dec, catb);
    // E: proj GEMM (bf16 MFMA) -> projb
    kE<<<dim3(48), blk, 0, stream>>>(catb, WpT, projb);
    // F: logits pass 1 (partials)
    kF<<<dim3(196), blk, 0, stream>>>(projb, Wt, partial);
    // R: reduce -> scale
    kRed<<<dim3(BTdim), blk, 0, stream>>>(partial, pg, scale);
    // G: logits pass 2 + fused scatter
    kG<<<dim3(392,2), blk, 0, stream>>>(projb, Wt, scale, pg, att, ev, out);
}

// Round 5
// 695.096 us; speedup vs baseline: 1.0745x; 1.0020x over previous
//
#include <hip/hip_runtime.h>
#include <hip/hip_bf16.h>
#include <cstdint>

typedef __attribute__((ext_vector_type(8))) short short8;
typedef __attribute__((ext_vector_type(4))) float floatx4;
typedef __attribute__((ext_vector_type(16))) float floatx16;

#define Bdim 32
#define Tdim 48
#define Ldim 400
#define Hdim 512
#define Edim 128
#define Vdim 50000
#define VEdim 50100
#define BTdim 1536
#define CATdim 1536
#define NPAD 50048     // 782*64; also 391*128
#define MTILES 96      // BTdim/16
#define NPART 782      // 64-col tiles in pass 1
#define NPSTRIDE 800   // padded row stride of partial[m][wid]

__device__ __forceinline__ short f2bf(float x){
    __hip_bfloat16 h = __float2bfloat16(x);
    union { __hip_bfloat16 h; short s; } u; u.h = h; return u.s;
}

__device__ __forceinline__ float wred(float s){
    #pragma unroll
    for (int off = 32; off; off >>= 1) s += __shfl_xor(s, off, 64);
    return s;
}

// ---------------- fp32 tiled GEMM body, C = A(MxK) @ B(KxN), row-major ----
// register double-buffer prefetch; optional bf16 output (template).
template<bool BF16>
__device__ __forceinline__ void gemm_nn_body(
    const float* __restrict__ A, int lda,
    const float* __restrict__ B, int ldb,
    float* __restrict__ C, short* __restrict__ Cb, int ldc,
    int M, int N, int K, int m0, int n0,
    float (*As)[68], float (*Bs)[68])
{
    const int tid = threadIdx.x;
    const int tx = tid & 15, ty = tid >> 4;
    const int ar = tid >> 2, ac = (tid & 3) * 4;   // A: row in tile, col*4
    const int br = tid >> 4, bc = (tid & 15) * 4;  // B: row in tile, col*4
    float acc[4][4] = {};
    float4 va = make_float4(0.f,0.f,0.f,0.f);
    float4 vb = make_float4(0.f,0.f,0.f,0.f);
    if (m0 + ar < M) va = *(const float4*)(A + (size_t)(m0+ar)*lda + ac);
    if (n0 + bc < N) vb = *(const float4*)(B + (size_t)br*ldb + n0 + bc);
    for (int k0 = 0; k0 < K; k0 += 16){
        As[ac+0][ar]=va.x; As[ac+1][ar]=va.y; As[ac+2][ar]=va.z; As[ac+3][ar]=va.w;
        Bs[br][bc+0]=vb.x; Bs[br][bc+1]=vb.y; Bs[br][bc+2]=vb.z; Bs[br][bc+3]=vb.w;
        __syncthreads();
        const int kn = k0 + 16;
        if (kn < K){
            va = make_float4(0.f,0.f,0.f,0.f);
            vb = make_float4(0.f,0.f,0.f,0.f);
            if (m0 + ar < M) va = *(const float4*)(A + (size_t)(m0+ar)*lda + kn + ac);
            if (n0 + bc < N) vb = *(const float4*)(B + (size_t)(kn+br)*ldb + n0 + bc);
        }
        #pragma unroll
        for (int k=0;k<16;k++){
            float a[4], b[4];
            #pragma unroll
            for (int i=0;i<4;i++) a[i] = As[k][ty*4+i];
            #pragma unroll
            for (int j=0;j<4;j++) b[j] = Bs[k][tx*4+j];
            #pragma unroll
            for (int i=0;i<4;i++)
                #pragma unroll
                for (int j=0;j<4;j++)
                    acc[i][j] += a[i]*b[j];
        }
        __syncthreads();
    }
    #pragma unroll
    for (int i=0;i<4;i++){
        int m = m0 + ty*4 + i;
        if (m >= M) continue;
        #pragma unroll
        for (int j=0;j<4;j++){
            int n = n0 + tx*4 + j;
            if (n < N){
                if (BF16) Cb[(size_t)m*ldc + n] = f2bf(acc[i][j]);
                else      C[(size_t)m*ldc + n]  = acc[i][j];
            }
        }
    }
}

// ---------------- fp32 tiled GEMM body, C = A(MxK) @ B(NxK)^T -------------
__device__ __forceinline__ void gemm_nt_body(
    const float* __restrict__ A, int lda,
    const float* __restrict__ B, int ldb,
    float* __restrict__ C, int ldc,
    int M, int N, int K, int m0, int n0,
    float (*As)[68], float (*Bs)[68])
{
    const int tid = threadIdx.x;
    const int tx = tid & 15, ty = tid >> 4;
    const int r = tid >> 2, c = (tid & 3) * 4;
    float acc[4][4] = {};
    float4 va = make_float4(0.f,0.f,0.f,0.f);
    float4 vb = make_float4(0.f,0.f,0.f,0.f);
    if (m0 + r < M) va = *(const float4*)(A + (size_t)(m0+r)*lda + c);
    if (n0 + r < N) vb = *(const float4*)(B + (size_t)(n0+r)*ldb + c);
    for (int k0 = 0; k0 < K; k0 += 16){
        As[c+0][r]=va.x; As[c+1][r]=va.y; As[c+2][r]=va.z; As[c+3][r]=va.w;
        Bs[c+0][r]=vb.x; Bs[c+1][r]=vb.y; Bs[c+2][r]=vb.z; Bs[c+3][r]=vb.w;
        __syncthreads();
        const int kn = k0 + 16;
        if (kn < K){
            va = make_float4(0.f,0.f,0.f,0.f);
            vb = make_float4(0.f,0.f,0.f,0.f);
            if (m0 + r < M) va = *(const float4*)(A + (size_t)(m0+r)*lda + kn + c);
            if (n0 + r < N) vb = *(const float4*)(B + (size_t)(n0+r)*ldb + kn + c);
        }
        #pragma unroll
        for (int k=0;k<16;k++){
            float a[4], b[4];
            #pragma unroll
            for (int i=0;i<4;i++) a[i] = As[k][ty*4+i];
            #pragma unroll
            for (int j=0;j<4;j++) b[j] = Bs[k][tx*4+j];
            #pragma unroll
            for (int i=0;i<4;i++)
                #pragma unroll
                for (int j=0;j<4;j++)
                    acc[i][j] += a[i]*b[j];
        }
        __syncthreads();
    }
    #pragma unroll
    for (int i=0;i<4;i++){
        int m = m0 + ty*4 + i;
        if (m >= M) continue;
        #pragma unroll
        for (int j=0;j<4;j++){
            int n = n0 + tx*4 + j;
            if (n < N) C[(size_t)m*ldc + n] = acc[i][j];
        }
    }
}

// ============ launch A: p12 GEMMs + h-copy(bf16) + Wv transpose +
//              Wproj transpose(bf16) + q_enc/q_dec ========================
__global__ __launch_bounds__(256) void kA(
    const float* __restrict__ dec, const float* __restrict__ Wenc,
    const float* __restrict__ Wdec, float* __restrict__ P1, float* __restrict__ P2,
    short* __restrict__ catb,
    const float* __restrict__ Wv, short* __restrict__ Wt,
    const float* __restrict__ Wproj, short* __restrict__ WpT,
    const float* __restrict__ enc, const float* __restrict__ wptr,
    float* __restrict__ q_enc, float* __restrict__ q_dec)
{
    __shared__ float As[16][68];
    __shared__ float Bs[16][68];
    int bid = blockIdx.x;
    if (bid < 384){
        int z = bid / 192, r = bid % 192;
        gemm_nn_body<false>(dec, Hdim, z ? Wdec : Wenc, Hdim,
                            z ? P2 : P1, nullptr, Hdim,
                            BTdim, Hdim, Hdim, (r>>3)*64, (r&7)*64, As, Bs);
        return;
    }
    bid -= 384;
    if (bid < 384){
        // copy h into catb[:, 0:512] as bf16; 8 elems/thread
        int idx = bid*256 + threadIdx.x;          // 0..98303
        int m = idx >> 6, j = (idx & 63) << 3;
        float4 v0 = *(const float4*)(dec + (size_t)m*Hdim + j);
        float4 v1 = *(const float4*)(dec + (size_t)m*Hdim + j + 4);
        short8 s;
        s[0]=f2bf(v0.x); s[1]=f2bf(v0.y); s[2]=f2bf(v0.z); s[3]=f2bf(v0.w);
        s[4]=f2bf(v1.x); s[5]=f2bf(v1.y); s[6]=f2bf(v1.z); s[7]=f2bf(v1.w);
        *(short8*)(catb + (size_t)m*CATdim + j) = s;
        return;
    }
    bid -= 384;
    if (bid < 6256){
        // W_vocab (128 x 50000) -> bf16 transposed (50048 x 128)
        float (*tile)[33] = reinterpret_cast<float(*)[33]>(&As[0][0]);  // 1056<=1088
        int n0 = (bid % 1564)*32, k0 = (bid / 1564)*32;
        int x = threadIdx.x & 31, y0 = threadIdx.x >> 5;  // 32 x 8
        for (int yy=y0; yy<32; yy+=8){
            int n = n0 + x;
            tile[yy][x] = (n < Vdim) ? Wv[(size_t)(k0+yy)*Vdim + n] : 0.f;
        }
        __syncthreads();
        for (int yy=y0; yy<32; yy+=8){
            int n = n0 + yy;
            if (n < NPAD) Wt[(size_t)n*Edim + k0 + x] = f2bf(tile[x][yy]);
        }
        return;
    }
    bid -= 6256;
    if (bid < 192){
        // Wproj (1536 x 128) -> bf16 transposed WpT (128 x 1536)
        float (*tile)[33] = reinterpret_cast<float(*)[33]>(&As[0][0]);
        int k0 = (bid / 4)*32, n0 = (bid % 4)*32;
        int x = threadIdx.x & 31, y0 = threadIdx.x >> 5;
        for (int yy=y0; yy<32; yy+=8)
            tile[yy][x] = Wproj[(size_t)(k0+yy)*Edim + n0 + x];
        __syncthreads();
        for (int yy=y0; yy<32; yy+=8)
            WpT[(size_t)(n0+yy)*CATdim + k0 + x] = f2bf(tile[x][yy]);
        return;
    }
    bid -= 192;
    {
        // q_enc[b][l] = enc[b][l] . w2 ; q_dec[b][t] = dec[b][t] . w3
        int b = bid >> 2, part = bid & 3;
        int wv = threadIdx.x >> 6, lane = threadIdx.x & 63;
        const float* w2 = wptr + Hdim;
        const float* w3 = wptr + 2*Hdim;
        for (int r = part*100 + wv; r < part*100 + 100; r += 4){
            const float* rp = enc + ((size_t)b*Ldim + r)*Hdim;
            float s = 0.f;
            #pragma unroll
            for (int i = 0; i < 8; i++) s += rp[lane + i*64]*w2[lane + i*64];
            s = wred(s);
            if (lane == 0) q_enc[b*Ldim + r] = s;
        }
        if (part == 0){
            for (int r = wv; r < Tdim; r += 4){
                const float* rp = dec + ((size_t)b*Tdim + r)*Hdim;
                float s = 0.f;
                #pragma unroll
                for (int i = 0; i < 8; i++) s += rp[lane + i*64]*w3[lane + i*64];
                s = wred(s);
                if (lane == 0) q_dec[b*Tdim + r] = s;
            }
        }
    }
}

// ============ launch B: e-scores + s-scores (NT GEMMs) ====================
__global__ __launch_bounds__(256) void kB(
    const float* __restrict__ P1, const float* __restrict__ P2,
    const float* __restrict__ enc, const float* __restrict__ dec,
    float* __restrict__ ebuf, float* __restrict__ sbuf)
{
    __shared__ float As[16][68];
    __shared__ float Bs[16][68];
    int bid = blockIdx.x;
    if (bid < 224){
        int z = bid / 7, x = bid % 7;
        gemm_nt_body(P1 + (size_t)z*Tdim*Hdim, Hdim,
                     enc + (size_t)z*Ldim*Hdim, Hdim,
                     ebuf + (size_t)z*Tdim*Ldim, Ldim,
                     Tdim, Ldim, Hdim, 0, x*64, As, Bs);
    } else {
        int z = bid - 224;
        gemm_nt_body(P2 + (size_t)z*Tdim*Hdim, Hdim,
                     dec + (size_t)z*Tdim*Hdim, Hdim,
                     sbuf + (size_t)z*Tdim*Tdim, Tdim,
                     Tdim, Tdim, Hdim, 0, 0, As, Bs);
    }
}

// ============ launch C: per-b temporal scan + l-normalize + masked decoder
//              softmax + pointer gate. 32 blocks x 512 threads. =============
__global__ __launch_bounds__(512) void kC(
    const float* __restrict__ e, float* __restrict__ att, float* __restrict__ sbuf,
    const float* __restrict__ dec, const float* __restrict__ wptr,
    const float* __restrict__ bptr,
    const float* __restrict__ q_enc, const float* __restrict__ q_dec,
    float* __restrict__ pg)
{
    __shared__ float att_s[Tdim][Ldim];   // 75 KB
    __shared__ float dE[Tdim], dD[Tdim], dH[Tdim];
    const int b = blockIdx.x;
    const int tid = threadIdx.x;
    // temporal prefix scan over t (one thread per l)
    if (tid < Ldim){
        const float* ep = e + (size_t)b*Tdim*Ldim + tid;
        float acc = 0.f;
        for (int t = 0; t < Tdim; ++t){
            float x = __expf(ep[t*Ldim]);
            att_s[t][tid] = x / (t ? acc : 1.f);
            acc += x;
        }
    }
    __syncthreads();
    const int wv = tid >> 6, lane = tid & 63;
    // per-row normalize + dot with q_enc; write normalized att to global
    for (int t = wv; t < Tdim; t += 8){
        float s1 = 0.f, s2 = 0.f;
        for (int l = lane; l < Ldim; l += 64){
            float a = att_s[t][l];
            s1 += a;
            s2 += a * q_enc[b*Ldim + l];
        }
        s1 = wred(s1); s2 = wred(s2);
        float inv = 1.f/s1;
        if (lane == 0) dE[t] = s2*inv;
        for (int l = lane; l < Ldim; l += 64)
            att[(size_t)(b*Tdim + t)*Ldim + l] = att_s[t][l]*inv;
    }
    // h . w1 per row
    for (int t = wv; t < Tdim; t += 8){
        const float* hp = dec + ((size_t)b*Tdim + t)*Hdim;
        float s = 0.f;
        #pragma unroll
        for (int i = 0; i < 8; i++) s += hp[lane + i*64]*wptr[lane + i*64];
        s = wred(s);
        if (lane == 0) dH[t] = s;
    }
    // masked decoder softmax per row + dot with q_dec
    for (int t = wv; t < Tdim; t += 8){
        float* row = sbuf + ((size_t)b*Tdim + t)*Tdim;
        if (t == 0){
            if (lane < Tdim) row[lane] = 0.f;
            if (lane == 0) dD[0] = 0.f;
        } else {
            float v = (lane < t) ? row[lane] : -1e30f;
            float mx = v;
            #pragma unroll
            for (int off = 32; off; off >>= 1) mx = fmaxf(mx, __shfl_xor(mx, off, 64));
            float ex = (lane < t) ? __expf(v - mx) : 0.f;
            float sm = wred(ex);
            float nv = ex / sm;
            if (lane < Tdim) row[lane] = nv;
            float d = (lane < Tdim) ? nv * q_dec[b*Tdim + lane] : 0.f;
            d = wred(d);
            if (lane == 0) dD[t] = d;
        }
    }
    __syncthreads();
    if (tid < Tdim){
        float tot = dH[tid] + dE[tid] + dD[tid] + bptr[0];
        pg[b*Tdim + tid] = 1.f/(1.f + __expf(-tot));
    }
}

// ============ launch D: enc_ctx + dec_ctx GEMMs into catb (bf16) ==========
__global__ __launch_bounds__(256) void kD(
    const float* __restrict__ att, const float* __restrict__ sbuf,
    const float* __restrict__ enc, const float* __restrict__ dec,
    short* __restrict__ catb)
{
    __shared__ float As[16][68];
    __shared__ float Bs[16][68];
    int bid = blockIdx.x;
    if (bid < 256){
        int z = bid >> 3, x = bid & 7;
        gemm_nn_body<true>(att + (size_t)z*Tdim*Ldim, Ldim,
                           enc + (size_t)z*Ldim*Hdim, Hdim,
                           nullptr, catb + (size_t)z*Tdim*CATdim + Hdim, CATdim,
                           Tdim, Hdim, Ldim, 0, x*64, As, Bs);
    } else {
        int r = bid - 256;
        int z = r >> 3, x = r & 7;
        gemm_nn_body<true>(sbuf + (size_t)z*Tdim*Tdim, Tdim,
                           dec + (size_t)z*Tdim*Hdim, Hdim,
                           nullptr, catb + (size_t)z*Tdim*CATdim + 2*Hdim, CATdim,
                           Tdim, Hdim, Tdim, 0, x*64, As, Bs);
    }
}

// ============ launch E: proj GEMM via bf16 MFMA ===========================
// projb[m][n] = sum_k catb[m][k]*WpT[n][k]; block = one 32-row tile of m,
// 4 waves cover n = 0..127.
__global__ __launch_bounds__(256) void kE(
    const short* __restrict__ catb, const short* __restrict__ WpT,
    short* __restrict__ projb)
{
    const int lane = threadIdx.x & 63;
    const int wave = threadIdx.x >> 6;
    const int l31 = lane & 31, half = lane >> 5;
    const int mt = blockIdx.x;           // 0..47
    const int n0 = wave*32;
    const short* ap = catb + (size_t)(mt*32 + l31)*CATdim + half*8;
    const short* bp = WpT  + (size_t)(n0 + l31)*CATdim + half*8;
    floatx16 acc;
    #pragma unroll
    for (int i=0;i<16;i++) acc[i] = 0.f;
    #pragma unroll 4
    for (int kk=0;kk<96;kk++){
        short8 af = *(const short8*)(ap + kk*16);
        short8 bf = *(const short8*)(bp + kk*16);
        acc = __builtin_amdgcn_mfma_f32_32x32x16_bf16(af, bf, acc, 0, 0, 0);
    }
    #pragma unroll
    for (int r=0;r<16;r++){
        int m = mt*32 + (r&3) + 8*(r>>2) + 4*half;
        projb[(size_t)m*Edim + n0 + l31] = f2bf(acc[r]);
    }
}

// ============ launch F: logits pass 1 — per-row exp-sum partials ==========
// Swapped-operand 16x16x32 MFMA: m is lane-local (lane&15); 64-col sum needs
// only 2 shfl_xor stages; lane<16 stores to partial[m][wid] (stride 800) so
// kRed reads coalesced rows. mt range split over blockIdx.y for occupancy.
__global__ __launch_bounds__(256) void kF(
    const short* __restrict__ Ab, const short* __restrict__ Bt,
    float* __restrict__ partial)
{
    const int lane = threadIdx.x & 63;
    const int wave = threadIdx.x >> 6;
    const int l15 = lane & 15, quad = lane >> 4;
    const int wid = blockIdx.x*4 + wave;
    if (wid >= NPART) return;
    const int n0 = wid*64;
    short8 bfrag[4][4];
    #pragma unroll
    for (int ct=0;ct<4;ct++){
        const short* bp = Bt + (size_t)(n0 + ct*16 + l15)*Edim + quad*8;
        #pragma unroll
        for (int kk=0;kk<4;kk++) bfrag[ct][kk] = *(const short8*)(bp + kk*32);
    }
    float vmask[4];
    #pragma unroll
    for (int ct=0;ct<4;ct++) vmask[ct] = (n0 + ct*16 < Vdim) ? 1.f : 0.f;

    auto loadA = [&](int mt, short8 (&af)[4]){
        const short* ap = Ab + (size_t)(mt*16 + l15)*Edim + quad*8;
        #pragma unroll
        for (int kk=0;kk<4;kk++) af[kk] = *(const short8*)(ap + kk*32);
    };
    auto compute = [&](int mt, short8 (&af)[4]){
        floatx4 a0 = {0.f,0.f,0.f,0.f};
        floatx4 a1 = a0, a2 = a0, a3 = a0;
        #pragma unroll
        for (int kk=0;kk<4;kk++){
            a0 = __builtin_amdgcn_mfma_f32_16x16x32_bf16(bfrag[0][kk], af[kk], a0, 0, 0, 0);
            a1 = __builtin_amdgcn_mfma_f32_16x16x32_bf16(bfrag[1][kk], af[kk], a1, 0, 0, 0);
            a2 = __builtin_amdgcn_mfma_f32_16x16x32_bf16(bfrag[2][kk], af[kk], a2, 0, 0, 0);
            a3 = __builtin_amdgcn_mfma_f32_16x16x32_bf16(bfrag[3][kk], af[kk], a3, 0, 0, 0);
        }
        float s = vmask[0]*(__expf(a0[0])+__expf(a0[1])+__expf(a0[2])+__expf(a0[3]))
                + vmask[1]*(__expf(a1[0])+__expf(a1[1])+__expf(a1[2])+__expf(a1[3]))
                + vmask[2]*(__expf(a2[0])+__expf(a2[1])+__expf(a2[2])+__expf(a2[3]))
                + vmask[3]*(__expf(a3[0])+__expf(a3[1])+__expf(a3[2])+__expf(a3[3]));
        s += __shfl_xor(s, 16, 64);
        s += __shfl_xor(s, 32, 64);
        if (lane < 16)
            partial[(size_t)(mt*16 + l15)*NPSTRIDE + wid] = s;
    };

    const int mt0 = blockIdx.y*48, mt1 = mt0 + 48;
    short8 afA[4], afB[4];
    loadA(mt0, afA);
    for (int mt=mt0; mt<mt1; mt+=2){
        loadA(mt+1, afB);
        compute(mt, afA);
        if (mt+2 < mt1) loadA(mt+2, afA);
        compute(mt+1, afB);
    }
}

// ============ launch R: reduce partials -> scale = (1-p)/S ================
__global__ __launch_bounds__(256) void kRed(const float* __restrict__ partial,
                         const float* __restrict__ pg, float* __restrict__ scale){
    int m = blockIdx.x;
    float s = 0.f;
    for (int w = threadIdx.x; w < NPART; w += 256)
        s += partial[(size_t)m*NPSTRIDE + w];
    #pragma unroll
    for (int off=32; off; off>>=1) s += __shfl_down(s, off, 64);
    __shared__ float red[4];
    if ((threadIdx.x&63)==0) red[threadIdx.x>>6]=s;
    __syncthreads();
    if (threadIdx.x==0)
        scale[m] = (1.f - pg[m]) / (red[0]+red[1]+red[2]+red[3]);
}

// ============ launch G: logits pass 2 + fused pointer scatter ==============
// Block (x,y) owns rows [y*384, y*384+384) x cols [x*128, x*128+128).
// __syncthreads drains vmcnt -> stores complete before the block's own
// scatter atomics to the same region (same-CU, same-L2).
__global__ __launch_bounds__(256) void kG(
    const short* __restrict__ Ab, const short* __restrict__ Bt,
    const float* __restrict__ scale, const float* __restrict__ pg,
    const float* __restrict__ att, const int* __restrict__ ev,
    float* __restrict__ out)
{
    __shared__ float scl[384];
    __shared__ int hits[3200];
    __shared__ int hcnt;
    const int lane = threadIdx.x & 63;
    const int wave = threadIdx.x >> 6;
    const int l31 = lane & 31, half = lane >> 5;
    const int n0 = blockIdx.x*128 + wave*32;
    const int n = n0 + l31;
    const int yoff = blockIdx.y*384;
    const int mt0 = blockIdx.y*12;
    for (int i = threadIdx.x; i < 384; i += 256)
        scl[i] = scale[yoff + i];
    if (threadIdx.x == 0) hcnt = 0;
    __syncthreads();

    if (n0 >= Vdim){
        if (n < VEdim){
            for (int mt=mt0; mt<mt0+12; ++mt){
                #pragma unroll
                for (int r=0;r<16;r++){
                    int m = mt*32 + (r&3) + 8*(r>>2) + 4*half;
                    out[(size_t)m*VEdim + n] = 0.f;
                }
            }
        }
    } else {
        short8 bfrag[8];
        const short* bp = Bt + (size_t)n*Edim + half*8;
        #pragma unroll
        for (int kk=0;kk<8;kk++) bfrag[kk] = *(const short8*)(bp + kk*16);
        const bool valid = n < Vdim;
        for (int mt=mt0; mt<mt0+12; ++mt){
            floatx16 acc;
            #pragma unroll
            for (int i=0;i<16;i++) acc[i] = 0.f;
            const short* ap = Ab + (size_t)(mt*32 + l31)*Edim + half*8;
            #pragma unroll
            for (int kk=0;kk<8;kk++){
                short8 af = *(const short8*)(ap + kk*16);
                acc = __builtin_amdgcn_mfma_f32_32x32x16_bf16(af, bfrag[kk], acc, 0, 0, 0);
            }
            #pragma unroll
            for (int r=0;r<16;r++){
                int m = mt*32 + (r&3) + 8*(r>>2) + 4*half;
                if (valid) out[(size_t)m*VEdim + n] = scl[m - yoff]*__expf(acc[r]);
                else if (n < VEdim) out[(size_t)m*VEdim + n] = 0.f;
            }
        }
    }
    // -------- fused scatter: ev hits of this block's 8 batches / col range -
    for (int idx = threadIdx.x; idx < 8*Ldim; idx += 256){
        int b = (blockIdx.y << 3) + idx/Ldim;
        int l = idx % Ldim;
        int v = ev[b*Ldim + l];
        if ((v >> 7) == (int)blockIdx.x){
            int h = atomicAdd(&hcnt, 1);
            hits[h] = (v << 14) | ((b & 31) << 9) | l;
        }
    }
    __syncthreads();
    const int tot = hcnt * Tdim;
    for (int j = threadIdx.x; j < tot; j += 256){
        int h = j / Tdim, t = j % Tdim;
        int pk = hits[h];
        int v = pk >> 14;
        int b = (pk >> 9) & 31;
        int l = pk & 511;
        int m = b*Tdim + t;
        atomicAdd(&out[(size_t)m*VEdim + v], pg[m]*att[(size_t)m*Ldim + l]);
    }
}

extern "C" void kernel_launch(void* const* d_in, const int* in_sizes, int n_in,
                              void* d_out, int out_size, void* d_ws, size_t ws_size,
                              hipStream_t stream)
{
    const float* dec  = (const float*)d_in[0];
    const float* enc  = (const float*)d_in[1];
    const float* Wenc = (const float*)d_in[2];
    const float* Wdec = (const float*)d_in[3];
    const float* Wproj= (const float*)d_in[4];
    const float* Wvoc = (const float*)d_in[5];
    const float* wptr = (const float*)d_in[6];
    const float* bptr = (const float*)d_in[7];
    const int*   ev   = (const int*)d_in[8];
    float* out = (float*)d_out;

    float* ws = (float*)d_ws;
    float* P1    = ws;                   // 1536x512
    float* P2    = P1 + 786432;          // 1536x512
    float* ebuf  = P2 + 786432;          // 32x48x400
    float* att   = ebuf + 614400;        // 32x48x400
    float* sbuf  = att + 614400;         // 32x48x48
    float* q_enc = sbuf + 73728;         // 32x400
    float* q_dec = q_enc + 12800;        // 32x48
    float* pg    = q_dec + 1536;         // 1536
    float* scale = pg + 1536;            // 1536
    float* partial = scale + 1536;       // 1536 x 800
    short* catb  = (short*)(partial + (size_t)BTdim*NPSTRIDE);  // 1536x1536 bf16
    short* projb = catb + (size_t)BTdim*CATdim;   // 1536x128 bf16
    short* WpT   = projb + 196608;                // 128x1536 bf16
    short* Wt    = WpT + 196608;                  // 50048x128 bf16

    dim3 blk(256);
    // A: p12 GEMMs (384) + h->catb (384) + Wv transpose (6256)
    //    + Wproj transpose (192) + qenc/qdec (128)
    kA<<<dim3(7344), blk, 0, stream>>>(dec, Wenc, Wdec, P1, P2, catb,
                                       Wvoc, Wt, Wproj, WpT, enc, wptr,
                                       q_enc, q_dec);
    // B: e-scores (224) + s-scores (32)
    kB<<<dim3(256), blk, 0, stream>>>(P1, P2, enc, dec, ebuf, sbuf);
    // C: temporal scan + normalize + decoder softmax + pgate (per b)
    kC<<<dim3(Bdim), dim3(512), 0, stream>>>(ebuf, att, sbuf, dec, wptr, bptr,
                                             q_enc, q_dec, pg);
    // D: enc_ctx (256) + dec_ctx (256) GEMMs -> catb
    kD<<<dim3(512), blk, 0, stream>>>(att, sbuf, enc, dec, catb);
    // E: proj GEMM (bf16 MFMA) -> projb
    kE<<<dim3(48), blk, 0, stream>>>(catb, WpT, projb);
    // F: logits pass 1 (partials), mt-split x2
    kF<<<dim3(196,2), blk, 0, stream>>>(projb, Wt, partial);
    // R: reduce -> scale
    kRed<<<dim3(BTdim), blk, 0, stream>>>(partial, pg, scale);
    // G: logits pass 2 + fused scatter, y=4
    kG<<<dim3(392,4), blk, 0, stream>>>(projb, Wt, scale, pg, att, ev, out);
}